// Round 2
// baseline (290.338 us; speedup 1.0000x reference)
//
#include <hip/hip_runtime.h>
#include <math.h>

#define G_    256
#define N_    2048
#define C_    512
#define POOL_ 32
#define BIN_  64      // N_/POOL_
#define HID_  64
#define HHALF_ 32     // HID_/2
#define C4_   128     // C_/4
#define HT_S  36      // LDS row stride for hT (floats): multiple of 4 -> 16B-aligned rows
#define H2_S  36
#define LN_EPS_ 1e-5f

__device__ __forceinline__ float wave_reduce_sum64(float v) {
    #pragma unroll
    for (int m = 1; m < 64; m <<= 1) v += __shfl_xor(v, m, 64);
    return v;
}

// ---------------- Kernel A: AdaptiveAvgPool1d(32) ----------------
// One block per (graph, pool-bin): sums 64 rows x 512 ch, writes pooled [g][p][c].
// 2 KB LDS, low VGPR -> 8 blocks/CU resident -> latency fully hidden.
__global__ __launch_bounds__(256) void pool_kernel(
    const float* __restrict__ x, float* __restrict__ pooled)
{
    __shared__ float4 part[C4_];
    const int b = blockIdx.x;          // bin id: g = b>>5, p = b&31
    const int t = threadIdx.x;
    const int c4   = t & 127;
    const int half = t >> 7;           // 0: rows 0..31, 1: rows 32..63

    const float4* x4 = (const float4*)x;
    const size_t base = ((size_t)b * BIN_ + (size_t)half * 32) * C4_ + c4;
    float sx = 0.f, sy = 0.f, sz = 0.f, sw = 0.f;
    #pragma unroll
    for (int r = 0; r < 32; ++r) {
        float4 v = x4[base + (size_t)r * C4_];
        sx += v.x; sy += v.y; sz += v.z; sw += v.w;
    }
    if (half) part[c4] = make_float4(sx, sy, sz, sw);
    __syncthreads();
    if (!half) {
        const float4 o = part[c4];
        const float inv = 1.0f / 64.0f;
        float4 r;
        r.x = (sx + o.x) * inv;
        r.y = (sy + o.y) * inv;
        r.z = (sz + o.z) * inv;
        r.w = (sw + o.w) * inv;
        ((float4*)pooled)[(size_t)b * C4_ + c4] = r;
    }
}

// ---------------- Kernel B: conv1 -> conv2 -> fc1 -> LN -> fc2 -> LN -> head ----------------
__global__ __launch_bounds__(256) void tail_kernel(
    const float* __restrict__ pooled,
    const float* __restrict__ c1w, const float* __restrict__ c1b,
    const float* __restrict__ c2w, const float* __restrict__ c2b,
    const float* __restrict__ f1w, const float* __restrict__ f1b,
    const float* __restrict__ f2w, const float* __restrict__ f2b,
    const float* __restrict__ lng, const float* __restrict__ lnb,
    const float* __restrict__ ow,  const float* __restrict__ ob,
    float* __restrict__ out)
{
    __shared__ __align__(16) float hT[C_ * HT_S];        // pooled, transposed: [c][p]
    __shared__ __align__(16) float h2[HID_ * H2_S];      // conv1 output: [co][l]
    __shared__ __align__(16) float f3[HHALF_ * POOL_];   // conv2 output, flat [co*32 + l]
    __shared__ float p4[256];                            // fc partial sums
    __shared__ __align__(16) float aLDS[HID_];           // post-LN activations

    const int g = blockIdx.x;
    const int t = threadIdx.x;

    // ---------- Phase 1': load pooled [p][c] -> LDS transposed hT[c][p] ----------
    {
        const float4* p4g = (const float4*)(pooled + (size_t)g * POOL_ * C_);
        #pragma unroll
        for (int i = 0; i < 16; ++i) {
            const int idx = t + i * 256;       // 0..4095 float4s
            const int p   = idx >> 7;          // wave-uniform per i
            const int c4  = idx & 127;
            const float4 v = p4g[idx];
            const int c0 = c4 << 2;
            hT[(c0 + 0) * HT_S + p] = v.x;
            hT[(c0 + 1) * HT_S + p] = v.y;
            hT[(c0 + 2) * HT_S + p] = v.z;
            hT[(c0 + 3) * HT_S + p] = v.w;
        }
    }
    __syncthreads();

    // ---------- Phase 2: conv1 (512 -> 64, k=3, SAME) + bias + ReLU ----------
    {
        const int co    = t & 63;
        const int lbase = (t >> 6) << 3;   // 0,8,16,24 (wave-uniform)
        float acc[8];
        #pragma unroll
        for (int i = 0; i < 8; ++i) acc[i] = 0.f;
        const int   off_l = (lbase == 0)  ? lbase : (lbase - 1);
        const float ml    = (lbase == 0)  ? 0.f : 1.f;
        const int   off_r = (lbase == 24) ? lbase : (lbase + 8);
        const float mr    = (lbase == 24) ? 0.f : 1.f;
        const float* wbase = c1w + (size_t)co * (C_ * 3);
        #pragma unroll 2
        for (int cin = 0; cin < C_; ++cin) {
            const float* row = &hT[cin * HT_S];
            const float4 a0 = *(const float4*)&row[lbase];
            const float4 a1 = *(const float4*)&row[lbase + 4];
            float hv[10];
            hv[0] = row[off_l] * ml;
            hv[1] = a0.x; hv[2] = a0.y; hv[3] = a0.z; hv[4] = a0.w;
            hv[5] = a1.x; hv[6] = a1.y; hv[7] = a1.z; hv[8] = a1.w;
            hv[9] = row[off_r] * mr;
            const float* wp = wbase + cin * 3;
            const float w0 = wp[0], w1 = wp[1], w2 = wp[2];
            #pragma unroll
            for (int i = 0; i < 8; ++i)
                acc[i] = fmaf(w0, hv[i], fmaf(w1, hv[i + 1], fmaf(w2, hv[i + 2], acc[i])));
        }
        const float b = c1b[co];
        #pragma unroll
        for (int i = 0; i < 8; ++i)
            h2[co * H2_S + lbase + i] = fmaxf(acc[i] + b, 0.f);
    }
    __syncthreads();

    // ---------- Phase 3: conv2 (64 -> 32, k=3, SAME) + bias + ReLU, flatten ----------
    {
        const int co    = t & 31;
        const int lbase = (t >> 5) << 2;   // 0..28 step 4
        float acc[4] = {0.f, 0.f, 0.f, 0.f};
        const int   off_l = (lbase == 0)  ? lbase : (lbase - 1);
        const float ml    = (lbase == 0)  ? 0.f : 1.f;
        const int   off_r = (lbase == 28) ? lbase : (lbase + 4);
        const float mr    = (lbase == 28) ? 0.f : 1.f;
        const float* wbase = c2w + (size_t)co * (HID_ * 3);
        #pragma unroll 4
        for (int cin = 0; cin < HID_; ++cin) {
            const float* row = &h2[cin * H2_S];
            const float4 a0 = *(const float4*)&row[lbase];
            float hv[6];
            hv[0] = row[off_l] * ml;
            hv[1] = a0.x; hv[2] = a0.y; hv[3] = a0.z; hv[4] = a0.w;
            hv[5] = row[off_r] * mr;
            const float* wp = wbase + cin * 3;
            const float w0 = wp[0], w1 = wp[1], w2 = wp[2];
            #pragma unroll
            for (int i = 0; i < 4; ++i)
                acc[i] = fmaf(w0, hv[i], fmaf(w1, hv[i + 1], fmaf(w2, hv[i + 2], acc[i])));
        }
        const float b = c2b[co];
        #pragma unroll
        for (int i = 0; i < 4; ++i)
            f3[co * POOL_ + lbase + i] = fmaxf(acc[i] + b, 0.f);
    }
    __syncthreads();

    // ---------- Phase 4: fc1 (1024 -> 64) ----------
    {
        const int o = t >> 2, q = t & 3;
        const float4* wrow = (const float4*)(f1w + (size_t)o * 1024 + q * 256);
        const float4* frow = (const float4*)(f3 + q * 256);
        float s = 0.f;
        #pragma unroll
        for (int i = 0; i < 64; ++i) {
            const float4 wv = wrow[i], fv = frow[i];
            s = fmaf(wv.x, fv.x, s); s = fmaf(wv.y, fv.y, s);
            s = fmaf(wv.z, fv.z, s); s = fmaf(wv.w, fv.w, s);
        }
        p4[t] = s;
    }
    __syncthreads();
    if (t < 64) {
        float v = p4[t * 4] + p4[t * 4 + 1] + p4[t * 4 + 2] + p4[t * 4 + 3] + f1b[t];
        const float mu  = wave_reduce_sum64(v) * (1.0f / 64.0f);
        const float d   = v - mu;
        const float var = wave_reduce_sum64(d * d) * (1.0f / 64.0f);
        const float y   = d * rsqrtf(var + LN_EPS_) * lng[t] + lnb[t];
        aLDS[t] = fmaxf(y, 0.f);
    }
    __syncthreads();

    // ---------- Phase 5: fc2 (64 -> 64) ----------
    {
        const int o = t >> 2, q = t & 3;
        const float4* wrow = (const float4*)(f2w + (size_t)o * 64 + q * 16);
        float s = 0.f;
        #pragma unroll
        for (int i = 0; i < 4; ++i) {
            const float4 wv = wrow[i];
            const float4 av = *(const float4*)&aLDS[q * 16 + i * 4];
            s = fmaf(wv.x, av.x, s); s = fmaf(wv.y, av.y, s);
            s = fmaf(wv.z, av.z, s); s = fmaf(wv.w, av.w, s);
        }
        p4[t] = s;
    }
    __syncthreads();

    // ---------- Phase 6: LN + ReLU + output head ----------
    if (t < 64) {
        float v = p4[t * 4] + p4[t * 4 + 1] + p4[t * 4 + 2] + p4[t * 4 + 3] + f2b[t];
        const float mu  = wave_reduce_sum64(v) * (1.0f / 64.0f);
        const float d   = v - mu;
        const float var = wave_reduce_sum64(d * d) * (1.0f / 64.0f);
        const float y   = d * rsqrtf(var + LN_EPS_) * lng[t] + lnb[t];
        const float bb  = fmaxf(y, 0.f);
        const float tot = wave_reduce_sum64(bb * ow[t]);
        if (t == 0) out[g] = tot + ob[0];
    }
}

extern "C" void kernel_launch(void* const* d_in, const int* in_sizes, int n_in,
                              void* d_out, int out_size, void* d_ws, size_t ws_size,
                              hipStream_t stream) {
    const float* x   = (const float*)d_in[0];
    // d_in[1] = batch (int64) — unused: graphs are sorted and equal-sized
    const float* c1w = (const float*)d_in[2];
    const float* c1b = (const float*)d_in[3];
    const float* c2w = (const float*)d_in[4];
    const float* c2b = (const float*)d_in[5];
    const float* f1w = (const float*)d_in[6];
    const float* f1b = (const float*)d_in[7];
    const float* f2w = (const float*)d_in[8];
    const float* f2b = (const float*)d_in[9];
    const float* lng = (const float*)d_in[10];
    const float* lnb = (const float*)d_in[11];
    const float* ow  = (const float*)d_in[12];
    const float* ob  = (const float*)d_in[13];
    float* out = (float*)d_out;

    float* pooled = (float*)d_ws;   // 8192 * 512 * 4 B = 16 MB

    pool_kernel<<<G_ * POOL_, 256, 0, stream>>>(x, pooled);
    tail_kernel<<<G_, 256, 0, stream>>>(
        pooled, c1w, c1b, c2w, c2b, f1w, f1b, f2w, f2b, lng, lnb, ow, ob, out);

    (void)in_sizes; (void)n_in; (void)out_size; (void)ws_size;
}

// Round 4
// 233.687 us; speedup vs baseline: 1.2424x; 1.2424x over previous
//
#include <hip/hip_runtime.h>
#include <math.h>

#define G_    256
#define N_    2048
#define C_    512
#define POOL_ 32
#define BIN_  64      // N_/POOL_
#define HID_  64
#define HHALF_ 32     // HID_/2
#define C4_   128     // C_/4
#define HT_S  36      // LDS row stride for hT (floats): multiple of 4 -> 16B-aligned rows
#define H2_S  36
#define LN_EPS_ 1e-5f

typedef float vfloat4 __attribute__((ext_vector_type(4)));  // native vector: OK for nontemporal builtin

__device__ __forceinline__ float wave_reduce_sum64(float v) {
    #pragma unroll
    for (int m = 1; m < 64; m <<= 1) v += __shfl_xor(v, m, 64);
    return v;
}

__global__ __launch_bounds__(256) void fused_graphnet_kernel(
    const float* __restrict__ x,
    const float* __restrict__ c1w, const float* __restrict__ c1b,
    const float* __restrict__ c2w, const float* __restrict__ c2b,
    const float* __restrict__ f1w, const float* __restrict__ f1b,
    const float* __restrict__ f2w, const float* __restrict__ f2b,
    const float* __restrict__ lng, const float* __restrict__ lnb,
    const float* __restrict__ ow,  const float* __restrict__ ob,
    float* __restrict__ out)
{
    __shared__ __align__(16) float hT[C_ * HT_S];        // pooled, transposed: [c][p]
    __shared__ __align__(16) float h2[HID_ * H2_S];      // conv1 output: [co][l]
    __shared__ __align__(16) float f3[HHALF_ * POOL_];   // conv2 output, flat [co*32 + l]
    __shared__ float p4[256];                            // fc partial sums
    __shared__ __align__(16) float aLDS[HID_];           // post-LN activations

    const int g = blockIdx.x;
    const int t = threadIdx.x;

    // ---------- Phase 1: AdaptiveAvgPool1d(32), nontemporal streaming reads ----------
    // x is a 1.07 GB single-use stream: bypass L2/L3 allocation with nt loads.
    {
        const vfloat4* x4 = (const vfloat4*)x;
        const int c4  = t & 127;   // which float4 of the 512-ch row
        const int prg = t >> 7;    // 0/1: parity of pool bin
        #pragma unroll 1
        for (int it = 0; it < 16; ++it) {
            const int p = prg + (it << 1);
            const size_t base = ((size_t)g * N_ + (size_t)p * BIN_) * C4_ + c4;
            float sx = 0.f, sy = 0.f, sz = 0.f, sw = 0.f;
            #pragma unroll
            for (int r = 0; r < BIN_; ++r) {
                vfloat4 v = __builtin_nontemporal_load(&x4[base + (size_t)r * C4_]);
                sx += v.x; sy += v.y; sz += v.z; sw += v.w;
            }
            const float inv = 1.0f / 64.0f;
            const int c0 = c4 << 2;
            hT[(c0 + 0) * HT_S + p] = sx * inv;
            hT[(c0 + 1) * HT_S + p] = sy * inv;
            hT[(c0 + 2) * HT_S + p] = sz * inv;
            hT[(c0 + 3) * HT_S + p] = sw * inv;
        }
    }
    __syncthreads();

    // ---------- Phase 2: conv1 (512 -> 64, k=3, SAME) + bias + ReLU ----------
    {
        const int co    = t & 63;
        const int lbase = (t >> 6) << 3;   // 0,8,16,24 (wave-uniform)
        float acc[8];
        #pragma unroll
        for (int i = 0; i < 8; ++i) acc[i] = 0.f;
        const int   off_l = (lbase == 0)  ? lbase : (lbase - 1);
        const float ml    = (lbase == 0)  ? 0.f : 1.f;
        const int   off_r = (lbase == 24) ? lbase : (lbase + 8);
        const float mr    = (lbase == 24) ? 0.f : 1.f;
        const float* wbase = c1w + (size_t)co * (C_ * 3);
        #pragma unroll 2
        for (int cin = 0; cin < C_; ++cin) {
            const float* row = &hT[cin * HT_S];
            const float4 a0 = *(const float4*)&row[lbase];
            const float4 a1 = *(const float4*)&row[lbase + 4];
            float hv[10];
            hv[0] = row[off_l] * ml;
            hv[1] = a0.x; hv[2] = a0.y; hv[3] = a0.z; hv[4] = a0.w;
            hv[5] = a1.x; hv[6] = a1.y; hv[7] = a1.z; hv[8] = a1.w;
            hv[9] = row[off_r] * mr;
            const float* wp = wbase + cin * 3;
            const float w0 = wp[0], w1 = wp[1], w2 = wp[2];
            #pragma unroll
            for (int i = 0; i < 8; ++i)
                acc[i] = fmaf(w0, hv[i], fmaf(w1, hv[i + 1], fmaf(w2, hv[i + 2], acc[i])));
        }
        const float b = c1b[co];
        #pragma unroll
        for (int i = 0; i < 8; ++i)
            h2[co * H2_S + lbase + i] = fmaxf(acc[i] + b, 0.f);
    }
    __syncthreads();

    // ---------- Phase 3: conv2 (64 -> 32, k=3, SAME) + bias + ReLU, flatten ----------
    {
        const int co    = t & 31;
        const int lbase = (t >> 5) << 2;   // 0..28 step 4
        float acc[4] = {0.f, 0.f, 0.f, 0.f};
        const int   off_l = (lbase == 0)  ? lbase : (lbase - 1);
        const float ml    = (lbase == 0)  ? 0.f : 1.f;
        const int   off_r = (lbase == 28) ? lbase : (lbase + 4);
        const float mr    = (lbase == 28) ? 0.f : 1.f;
        const float* wbase = c2w + (size_t)co * (HID_ * 3);
        #pragma unroll 4
        for (int cin = 0; cin < HID_; ++cin) {
            const float* row = &h2[cin * H2_S];
            const float4 a0 = *(const float4*)&row[lbase];
            float hv[6];
            hv[0] = row[off_l] * ml;
            hv[1] = a0.x; hv[2] = a0.y; hv[3] = a0.z; hv[4] = a0.w;
            hv[5] = row[off_r] * mr;
            const float* wp = wbase + cin * 3;
            const float w0 = wp[0], w1 = wp[1], w2 = wp[2];
            #pragma unroll
            for (int i = 0; i < 4; ++i)
                acc[i] = fmaf(w0, hv[i], fmaf(w1, hv[i + 1], fmaf(w2, hv[i + 2], acc[i])));
        }
        const float b = c2b[co];
        #pragma unroll
        for (int i = 0; i < 4; ++i)
            f3[co * POOL_ + lbase + i] = fmaxf(acc[i] + b, 0.f);
    }
    __syncthreads();

    // ---------- Phase 4: fc1 (1024 -> 64) ----------
    {
        const int o = t >> 2, q = t & 3;
        const float4* wrow = (const float4*)(f1w + (size_t)o * 1024 + q * 256);
        const float4* frow = (const float4*)(f3 + q * 256);
        float s = 0.f;
        #pragma unroll
        for (int i = 0; i < 64; ++i) {
            const float4 wv = wrow[i], fv = frow[i];
            s = fmaf(wv.x, fv.x, s); s = fmaf(wv.y, fv.y, s);
            s = fmaf(wv.z, fv.z, s); s = fmaf(wv.w, fv.w, s);
        }
        p4[t] = s;
    }
    __syncthreads();
    if (t < 64) {
        float v = p4[t * 4] + p4[t * 4 + 1] + p4[t * 4 + 2] + p4[t * 4 + 3] + f1b[t];
        const float mu  = wave_reduce_sum64(v) * (1.0f / 64.0f);
        const float d   = v - mu;
        const float var = wave_reduce_sum64(d * d) * (1.0f / 64.0f);
        const float y   = d * rsqrtf(var + LN_EPS_) * lng[t] + lnb[t];
        aLDS[t] = fmaxf(y, 0.f);
    }
    __syncthreads();

    // ---------- Phase 5: fc2 (64 -> 64) ----------
    {
        const int o = t >> 2, q = t & 3;
        const float4* wrow = (const float4*)(f2w + (size_t)o * 64 + q * 16);
        float s = 0.f;
        #pragma unroll
        for (int i = 0; i < 4; ++i) {
            const float4 wv = wrow[i];
            const float4 av = *(const float4*)&aLDS[q * 16 + i * 4];
            s = fmaf(wv.x, av.x, s); s = fmaf(wv.y, av.y, s);
            s = fmaf(wv.z, av.z, s); s = fmaf(wv.w, av.w, s);
        }
        p4[t] = s;
    }
    __syncthreads();

    // ---------- Phase 6: LN + ReLU + output head ----------
    if (t < 64) {
        float v = p4[t * 4] + p4[t * 4 + 1] + p4[t * 4 + 2] + p4[t * 4 + 3] + f2b[t];
        const float mu  = wave_reduce_sum64(v) * (1.0f / 64.0f);
        const float d   = v - mu;
        const float var = wave_reduce_sum64(d * d) * (1.0f / 64.0f);
        const float y   = d * rsqrtf(var + LN_EPS_) * lng[t] + lnb[t];
        const float bb  = fmaxf(y, 0.f);
        const float tot = wave_reduce_sum64(bb * ow[t]);
        if (t == 0) out[g] = tot + ob[0];
    }
}

extern "C" void kernel_launch(void* const* d_in, const int* in_sizes, int n_in,
                              void* d_out, int out_size, void* d_ws, size_t ws_size,
                              hipStream_t stream) {
    const float* x   = (const float*)d_in[0];
    // d_in[1] = batch (int64) — unused: graphs are sorted and equal-sized
    const float* c1w = (const float*)d_in[2];
    const float* c1b = (const float*)d_in[3];
    const float* c2w = (const float*)d_in[4];
    const float* c2b = (const float*)d_in[5];
    const float* f1w = (const float*)d_in[6];
    const float* f1b = (const float*)d_in[7];
    const float* f2w = (const float*)d_in[8];
    const float* f2b = (const float*)d_in[9];
    const float* lng = (const float*)d_in[10];
    const float* lnb = (const float*)d_in[11];
    const float* ow  = (const float*)d_in[12];
    const float* ob  = (const float*)d_in[13];
    float* out = (float*)d_out;

    fused_graphnet_kernel<<<G_, 256, 0, stream>>>(
        x, c1w, c1b, c2w, c2b, f1w, f1b, f2w, f2b, lng, lnb, ow, ob, out);

    (void)in_sizes; (void)n_in; (void)out_size; (void)d_ws; (void)ws_size;
}